// Round 9
// baseline (599.249 us; speedup 1.0000x reference)
//
#include <hip/hip_runtime.h>
#include <hip/hip_bf16.h>

// ---------------------------------------------------------------------------
// SelfAttention fused pipeline — round 9.
//   B=8, L=1024, C=1024, H=16, D=64
// Tier 1 (ws >= 240 MiB): split-bf16 MFMA GEMMs + swapped-operand MFMA flash
//   attention. vs round 8:
//   - gemm1 epilogue now fuses bias + l2norm + scale + bf16-split for q/k
//     (qk_norm_split kernel eliminated; no fp32 qkv intermediate at all)
//   - attention stages KVBLK=128 per barrier pair (two 64-halves processed
//     sequentially with the identical inner body) -> half the barriers.
// Tier 2 (ws >= 144 MiB): split-bf16 MFMA GEMMs + fp32 flash attn.
// Tier 3 (else, needs 128 MiB): pure fp32 path.
// ---------------------------------------------------------------------------

#define LN100 4.6051701859880914f

typedef __attribute__((ext_vector_type(8))) short short8;
typedef __attribute__((ext_vector_type(4))) float f32x4;
typedef __attribute__((ext_vector_type(4))) unsigned int u32x4;

#define MFMA_BF16(a, b, c) __builtin_amdgcn_mfma_f32_16x16x32_bf16(a, b, c, 0, 0, 0)

__device__ __forceinline__ unsigned short f2bf(float f) {
  unsigned u = __float_as_uint(f);
  u += 0x7fffu + ((u >> 16) & 1u);          // RNE (no NaNs in this workload)
  return (unsigned short)(u >> 16);
}
__device__ __forceinline__ float bf2f(unsigned short h) {
  return __uint_as_float(((unsigned)h) << 16);
}
// pack two f32 -> u32 of {bf16(a) lo, bf16(b) hi}, RNE (v_cvt_pk path)
__device__ __forceinline__ unsigned int pkbf2(float a, float b) {
  union { __hip_bfloat162 t; unsigned int u; } c;
  c.t = __float22bfloat162_rn(make_float2(a, b));
  return c.u;
}

__device__ __forceinline__ float bias_sel0(const float* qb, const float* vb, int col) {
  if (col < 1024) return qb[col];
  if (col < 2048) return 0.0f;
  return vb[col - 2048];
}

#define G2L16(gp, lp) __builtin_amdgcn_global_load_lds( \
    (const __attribute__((address_space(1))) void*)(gp), \
    (__attribute__((address_space(3))) void*)(lp), 16, 0, 0)

// ---------------------------------------------------------------------------
// split fp32 -> (hi, lo) bf16 pair, 4 elems/thread
// ---------------------------------------------------------------------------
__global__ __launch_bounds__(256)
void split_f32_bf16(const float* __restrict__ in, unsigned short* __restrict__ hi,
                    unsigned short* __restrict__ lo, int n4)
{
  int i = blockIdx.x * blockDim.x + threadIdx.x;
  if (i >= n4) return;
  float4 v = ((const float4*)in)[i];
  ushort4 h, l;
  h.x = f2bf(v.x); l.x = f2bf(v.x - bf2f(h.x));
  h.y = f2bf(v.y); l.y = f2bf(v.y - bf2f(h.y));
  h.z = f2bf(v.z); l.z = f2bf(v.z - bf2f(h.z));
  h.w = f2bf(v.w); l.w = f2bf(v.w - bf2f(h.w));
  ((ushort4*)hi)[i] = h;
  ((ushort4*)lo)[i] = l;
}

// ---------------------------------------------------------------------------
// Split-bf16 MFMA GEMM.
// MODE 0 (tier-1 qkv GEMM):
//   q/k cols (<2048): fused bias + l2norm + scale_mul + split-bf16 write to
//     qkh/qkl [8192][2048]. Row sum-of-squares = per-lane sum over j + 16-lane
//     shfl_xor butterfly (wave's 64 cols == one head).
//   V cols (>=2048): transposed + column-permuted split bf16 vth/vtl
//     (storage col c = (kv&3)+((kv>>4)&1)*4+((kv>>2)&3)*8+32*(kv>>5)).
// MODE 1: proj GEMM (b0 bias, fp32 C). MODE 2: qkv GEMM plain fp32 (tier 2).
// ---------------------------------------------------------------------------
template <int MODE>
__global__ __launch_bounds__(256)
void gemm_nt_split(const unsigned short* __restrict__ Ah, const unsigned short* __restrict__ Al,
                   const unsigned short* __restrict__ Wh, const unsigned short* __restrict__ Wl,
                   const float* __restrict__ b0, const float* __restrict__ b1,
                   const float* __restrict__ scale_mul,
                   float* __restrict__ C,
                   unsigned short* __restrict__ qkh, unsigned short* __restrict__ qkl,
                   unsigned short* __restrict__ vth, unsigned short* __restrict__ vtl,
                   int M, int N, int K)
{
  __shared__ unsigned short sA[128 * 64];
  __shared__ unsigned short sW[128 * 64];

  const int tid  = threadIdx.x;
  const int lane = tid & 63;
  const int l15  = lane & 15, lg = lane >> 4;
  const int w    = tid >> 6;
  const int wr   = (w >> 1) << 6;
  const int wc   = (w & 1) << 6;
  const int m0   = blockIdx.y << 7;
  const int n0   = blockIdx.x << 7;

  f32x4 acc[4][4];
  #pragma unroll
  for (int i = 0; i < 4; ++i)
    #pragma unroll
    for (int j = 0; j < 4; ++j)
      acc[i][j] = (f32x4){0.f, 0.f, 0.f, 0.f};

  for (int k0 = 0; k0 < K; k0 += 32) {
    __syncthreads();
    #pragma unroll
    for (int u = 0; u < 4; ++u) {
      int idx = (u << 8) + tid;
      int row = idx >> 3;
      int c   = idx & 7;
      int s   = c ^ (row & 7);
      size_t rbA = (size_t)(m0 + row) * K + k0;
      size_t rbW = (size_t)(n0 + row) * K + k0;
      const unsigned short* srcA = (s < 4) ? (Ah + rbA + (s << 3))
                                           : (Al + rbA + ((s - 4) << 3));
      const unsigned short* srcW = (s < 4) ? (Wh + rbW + (s << 3))
                                           : (Wl + rbW + ((s - 4) << 3));
      G2L16(srcA, sA + (idx << 3));
      G2L16(srcW, sW + (idx << 3));
    }
    __syncthreads();

    short8 ah[4], al[4];
    #pragma unroll
    for (int i = 0; i < 4; ++i) {
      int row = wr + (i << 4) + l15;
      ah[i] = *(const short8*)(sA + (row << 6) + ((lg       ^ (row & 7)) << 3));
      al[i] = *(const short8*)(sA + (row << 6) + (((4 + lg) ^ (row & 7)) << 3));
    }
    #pragma unroll
    for (int j = 0; j < 4; ++j) {
      int row = wc + (j << 4) + l15;
      short8 wh = *(const short8*)(sW + (row << 6) + ((lg       ^ (row & 7)) << 3));
      short8 wl = *(const short8*)(sW + (row << 6) + (((4 + lg) ^ (row & 7)) << 3));
      #pragma unroll
      for (int i = 0; i < 4; ++i) {
        acc[i][j] = MFMA_BF16(ah[i], wh, acc[i][j]);
        acc[i][j] = MFMA_BF16(ah[i], wl, acc[i][j]);
        acc[i][j] = MFMA_BF16(al[i], wh, acc[i][j]);
      }
    }
  }

  if (MODE == 0 && n0 >= 2048) {
    // ---- V third: transposed + column-permuted split bf16 (verified r8) ----
    #pragma unroll
    for (int j = 0; j < 4; ++j) {
      int col = n0 + wc + (j << 4) + l15;
      int d   = col - 2048;
      int hh  = d >> 6, dd = d & 63;
      float bb = b1[d];
      #pragma unroll
      for (int i = 0; i < 4; ++i) {
        int row  = m0 + wr + (i << 4) + (lg << 2);   // kv rows row..row+3
        int bidx = row >> 10;
        int l    = row & 1023;
        int cbase = (((l >> 4) & 1) << 2) + (((l >> 2) & 3) << 3) + ((l >> 5) << 5);
        size_t obase = ((((size_t)bidx << 4) + hh) << 6) + dd;
        obase = obase * 1024 + cbase;
        ushort4 hv, lv;
        float v0 = acc[i][j][0] + bb;
        float v1 = acc[i][j][1] + bb;
        float v2 = acc[i][j][2] + bb;
        float v3 = acc[i][j][3] + bb;
        hv.x = f2bf(v0); lv.x = f2bf(v0 - bf2f(hv.x));
        hv.y = f2bf(v1); lv.y = f2bf(v1 - bf2f(hv.y));
        hv.z = f2bf(v2); lv.z = f2bf(v2 - bf2f(hv.z));
        hv.w = f2bf(v3); lv.w = f2bf(v3 - bf2f(hv.w));
        *(ushort4*)(vth + obase) = hv;
        *(ushort4*)(vtl + obase) = lv;
      }
    }
  } else if (MODE == 0) {
    // ---- q/k thirds: fused bias + l2norm + scale + split-bf16 write ----
    const int colbase = n0 + wc;                   // multiple of 64
    const int third   = colbase >> 10;             // 0=q, 1=k
    const int h       = (colbase >> 6) & 15;
    const float sm    = (third == 0) ? __expf(fminf(scale_mul[h], LN100)) : 1.0f;
    if (third == 0) {
      #pragma unroll
      for (int j = 0; j < 4; ++j) {
        float bb = b0[colbase + (j << 4) + l15];   // q_bias
        #pragma unroll
        for (int i = 0; i < 4; ++i)
          #pragma unroll
          for (int r = 0; r < 4; ++r) acc[i][j][r] += bb;
      }
    }
    // row sum of squares over this wave's 64 cols (= one head's D=64)
    float ss[4][4];
    #pragma unroll
    for (int i = 0; i < 4; ++i)
      #pragma unroll
      for (int r = 0; r < 4; ++r)
        ss[i][r] = acc[i][0][r] * acc[i][0][r] + acc[i][1][r] * acc[i][1][r]
                 + acc[i][2][r] * acc[i][2][r] + acc[i][3][r] * acc[i][3][r];
    #pragma unroll
    for (int off = 1; off < 16; off <<= 1)
      #pragma unroll
      for (int i = 0; i < 4; ++i)
        #pragma unroll
        for (int r = 0; r < 4; ++r)
          ss[i][r] += __shfl_xor(ss[i][r], off);
    #pragma unroll
    for (int i = 0; i < 4; ++i)
      #pragma unroll
      for (int r = 0; r < 4; ++r) {
        float inv = sm / fmaxf(sqrtf(ss[i][r]), 1e-12f);
        int row = m0 + wr + (i << 4) + (lg << 2) + r;
        size_t ob = (size_t)row * 2048 + (third << 10) + (h << 6) + l15;
        #pragma unroll
        for (int j = 0; j < 4; ++j) {
          float v = acc[i][j][r] * inv;
          unsigned short hb = f2bf(v);
          qkh[ob + (j << 4)] = hb;
          qkl[ob + (j << 4)] = f2bf(v - bf2f(hb));
        }
      }
  } else {
    #pragma unroll
    for (int j = 0; j < 4; ++j) {
      int col = n0 + wc + (j << 4) + l15;
      float bb = (MODE == 1) ? b0[col] : bias_sel0(b0, b1, col);
      #pragma unroll
      for (int i = 0; i < 4; ++i) {
        int rbase = m0 + wr + (i << 4) + (lg << 2);
        #pragma unroll
        for (int r = 0; r < 4; ++r)
          C[(size_t)(rbase + r) * N + col] = acc[i][j][r] + bb;
      }
    }
  }
}

// ---------------------------------------------------------------------------
// Swapped-operand split-bf16 MFMA flash attention, QBLK=128, KVBLK=128.
// Block = (b,h,128 q-rows), 4 waves; wave w owns q rows 32w..32w+31 as two
// 16-row fragments qf, processed sequentially (register pressure).
// Per kv-tile of 128: one barrier pair stages K(128x64) + permuted V^T(64x128),
// then the verified 64-wide inner body runs for both halves hh=0,1.
// S^T = mfma(A=K, B=Q), C seeded by bias; softmax lane-local; PV with packed
// in-register P and one ds_read_b128 per (ks,jd). No P LDS. LDS = 64 KiB.
// ---------------------------------------------------------------------------
__global__ __launch_bounds__(256, 2)
void attn_mfma(const unsigned short* __restrict__ qk_h, const unsigned short* __restrict__ qk_l,
               const unsigned short* __restrict__ vth, const unsigned short* __restrict__ vtl,
               const float* __restrict__ bias,
               unsigned short* __restrict__ oh, unsigned short* __restrict__ ol)
{
  __shared__ unsigned short sKh[8192], sKl[8192];    // 128 kv rows x 64 u16
  __shared__ unsigned short sVh[8192], sVl[8192];    // 64 d rows x 128 u16 (perm)

  const int tid  = threadIdx.x;
  const int lane = tid & 63;
  const int l15  = lane & 15, lg = lane >> 4;
  const int w    = tid >> 6;
  const int qt = blockIdx.x & 7;
  const int h  = (blockIdx.x >> 3) & 15;
  const int b  = blockIdx.x >> 7;
  const int q0 = qt << 7;

  // Q fragments (B-operand): lane l15 = q-row, chunk lg*8 + ks*32 over d
  short8 qh[2][2], qlo[2][2];
  #pragma unroll
  for (int qf = 0; qf < 2; ++qf) {
    size_t rb = ((size_t)((b << 10) + q0 + (w << 5) + (qf << 4) + l15)) * 2048
              + (h << 6) + (lg << 3);
    qh[qf][0]  = *(const short8*)(qk_h + rb);
    qh[qf][1]  = *(const short8*)(qk_h + rb + 32);
    qlo[qf][0] = *(const short8*)(qk_l + rb);
    qlo[qf][1] = *(const short8*)(qk_l + rb + 32);
  }

  f32x4 ao[2][4];            // [qf][jd] O: row q=lg*4+r, col d=jd*16+l15
  float mr[2], lr[2];        // per qf, this lane's q-row = l15
  #pragma unroll
  for (int qf = 0; qf < 2; ++qf) {
    #pragma unroll
    for (int j = 0; j < 4; ++j) ao[qf][j] = (f32x4){0.f, 0.f, 0.f, 0.f};
    mr[qf] = -3.0e38f; lr[qf] = 0.0f;
  }

  const unsigned short* kh_base = qk_h + 1024 + (h << 6);
  const unsigned short* kl_base = qk_l + 1024 + (h << 6);
  const size_t vbase = ((size_t)((b << 4) + h)) * 65536;
  const float* bias_base = bias + ((size_t)h << 20)
                         + (size_t)(q0 + (w << 5) + l15) * 1024 + (lg << 2);

  for (int kv0 = 0; kv0 < 1024; kv0 += 128) {
    __syncthreads();
    // ---- stage K (128x64) and perm-V^T (64x128), hi/lo, swizzled ----
    #pragma unroll
    for (int u = 0; u < 4; ++u) {
      int idx = (u << 8) + tid;        // 0..1023
      {
        int r = idx >> 3, c = idx & 7;
        int s = c ^ (r & 7);
        size_t krow = (size_t)((b << 10) + kv0 + r) * 2048 + (s << 3);
        G2L16(kh_base + krow, sKh + (idx << 3));
        G2L16(kl_base + krow, sKl + (idx << 3));
      }
      {
        int d = idx >> 4, cc = idx & 15;
        int s = (cc & 8) | ((cc ^ d) & 7);
        size_t vrow = vbase + (size_t)d * 1024 + kv0 + (s << 3);
        G2L16(vth + vrow, sVh + (idx << 3));
        G2L16(vtl + vrow, sVl + (idx << 3));
      }
    }
    __syncthreads();

    #pragma unroll
    for (int hh = 0; hh < 2; ++hh) {
      const int kvo = kv0 + (hh << 6);
      #pragma unroll
      for (int qf = 0; qf < 2; ++qf) {
        // ---- S^T = K.Q + bias (bias seeds the MFMA accumulator) ----
        f32x4 sv[4];
        #pragma unroll
        for (int j = 0; j < 4; ++j) {
          float4 bv = *(const float4*)(bias_base + (size_t)(qf << 4) * 1024
                                       + kvo + (j << 4));
          f32x4 a = (f32x4){bv.x, bv.y, bv.z, bv.w};
          int row = (hh << 6) + (j << 4) + l15;      // kv row in 128-tile
          int c0 = lg ^ (row & 7);
          int c1 = (lg + 4) ^ (row & 7);
          short8 kh0 = *(const short8*)(sKh + (row << 6) + (c0 << 3));
          short8 kl0 = *(const short8*)(sKl + (row << 6) + (c0 << 3));
          short8 kh1 = *(const short8*)(sKh + (row << 6) + (c1 << 3));
          short8 kl1 = *(const short8*)(sKl + (row << 6) + (c1 << 3));
          a = MFMA_BF16(kh0, qh[qf][0], a);
          a = MFMA_BF16(kl0, qh[qf][0], a);
          a = MFMA_BF16(kh0, qlo[qf][0], a);
          a = MFMA_BF16(kh1, qh[qf][1], a);
          a = MFMA_BF16(kl1, qh[qf][1], a);
          a = MFMA_BF16(kh1, qlo[qf][1], a);
          sv[j] = a;
        }

        // ---- softmax (lane-local 16 + xor16/xor32) ----
        float mx = -3.0e38f;
        #pragma unroll
        for (int j = 0; j < 4; ++j)
          #pragma unroll
          for (int r = 0; r < 4; ++r) mx = fmaxf(mx, sv[j][r]);
        mx = fmaxf(mx, __shfl_xor(mx, 16));
        mx = fmaxf(mx, __shfl_xor(mx, 32));
        float mn = fmaxf(mr[qf], mx);
        float al = __expf(mr[qf] - mn);
        mr[qf] = mn;
        float rs = 0.0f;
        #pragma unroll
        for (int j = 0; j < 4; ++j)
          #pragma unroll
          for (int r = 0; r < 4; ++r) {
            float e = __expf(sv[j][r] - mn);
            sv[j][r] = e;
            rs += e;
          }
        rs += __shfl_xor(rs, 16);
        rs += __shfl_xor(rs, 32);
        lr[qf] = lr[qf] * al + rs;
        // alpha -> O layout (q = lg*4+r) and rescale
        #pragma unroll
        for (int r = 0; r < 4; ++r) {
          float av = __shfl(al, (lg << 2) + r);
          #pragma unroll
          for (int jd = 0; jd < 4; ++jd) ao[qf][jd][r] *= av;
        }

        // ---- pack P per ks and accumulate O += P.V ----
        #pragma unroll
        for (int ks = 0; ks < 2; ++ks) {
          unsigned int h0 = pkbf2(sv[2*ks][0],     sv[2*ks][1]);
          unsigned int h1 = pkbf2(sv[2*ks][2],     sv[2*ks][3]);
          unsigned int h2 = pkbf2(sv[2*ks + 1][0], sv[2*ks + 1][1]);
          unsigned int h3 = pkbf2(sv[2*ks + 1][2], sv[2*ks + 1][3]);
          unsigned int l0 = pkbf2(sv[2*ks][0]     - __uint_as_float(h0 << 16),
                                  sv[2*ks][1]     - __uint_as_float(h0 & 0xffff0000u));
          unsigned int l1 = pkbf2(sv[2*ks][2]     - __uint_as_float(h1 << 16),
                                  sv[2*ks][3]     - __uint_as_float(h1 & 0xffff0000u));
          unsigned int l2 = pkbf2(sv[2*ks + 1][0] - __uint_as_float(h2 << 16),
                                  sv[2*ks + 1][1] - __uint_as_float(h2 & 0xffff0000u));
          unsigned int l3 = pkbf2(sv[2*ks + 1][2] - __uint_as_float(h3 << 16),
                                  sv[2*ks + 1][3] - __uint_as_float(h3 & 0xffff0000u));
          union { u32x4 u; short8 s; } ph, pl;
          ph.u = (u32x4){h0, h1, h2, h3};
          pl.u = (u32x4){l0, l1, l2, l3};
          #pragma unroll
          for (int jd = 0; jd < 4; ++jd) {
            int vr = (jd << 4) + l15;               // d row (perm cols, 128-wide)
            int c  = (hh << 3) | (((ks << 2) + lg) ^ (vr & 7));
            short8 vh = *(const short8*)(sVh + (vr << 7) + (c << 3));
            short8 vl = *(const short8*)(sVl + (vr << 7) + (c << 3));
            ao[qf][jd] = MFMA_BF16(ph.s, vh, ao[qf][jd]);
            ao[qf][jd] = MFMA_BF16(ph.s, vl, ao[qf][jd]);
            ao[qf][jd] = MFMA_BF16(pl.s, vh, ao[qf][jd]);
          }
        }
      }
    }
  }

  // epilogue: O /= l (broadcast l to O layout) ; write split bf16 att
  #pragma unroll
  for (int qf = 0; qf < 2; ++qf)
    #pragma unroll
    for (int r = 0; r < 4; ++r) {
      float lv  = __shfl(lr[qf], (lg << 2) + r);
      float inv = 1.0f / lv;
      size_t orow = ((size_t)((b << 10) + q0 + (w << 5) + (qf << 4) + (lg << 2) + r)) * 1024
                  + (h << 6) + l15;
      #pragma unroll
      for (int jd = 0; jd < 4; ++jd) {
        float v = ao[qf][jd][r] * inv;
        unsigned short hb = f2bf(v);
        oh[orow + (jd << 4)] = hb;
        ol[orow + (jd << 4)] = f2bf(v - bf2f(hb));
      }
    }
}

// ---------------------------------------------------------------------------
// fp32 fallback GEMM
// ---------------------------------------------------------------------------
template <int MODE>
__global__ __launch_bounds__(256)
void gemm_nt(const float* __restrict__ A, const float* __restrict__ Bw,
             const float* __restrict__ b0, const float* __restrict__ b1,
             float* __restrict__ C, int M, int N, int K)
{
  __shared__ float As[32][132];
  __shared__ float Bs[32][132];
  const int tid = threadIdx.x;
  const int tx = tid & 15, ty = tid >> 4;
  const int m0 = blockIdx.y << 7;
  const int n0 = blockIdx.x << 7;

  float acc[8][8];
  #pragma unroll
  for (int i = 0; i < 8; ++i)
    #pragma unroll
    for (int j = 0; j < 8; ++j) acc[i][j] = 0.0f;

  for (int k0 = 0; k0 < K; k0 += 32) {
    #pragma unroll
    for (int u = 0; u < 4; ++u) {
      int f   = tid + (u << 8);
      int row = f >> 3;
      int kk  = (f & 7) << 2;
      float4 av = *(const float4*)(A  + (size_t)(m0 + row) * K + k0 + kk);
      As[kk + 0][row] = av.x; As[kk + 1][row] = av.y;
      As[kk + 2][row] = av.z; As[kk + 3][row] = av.w;
      float4 bv = *(const float4*)(Bw + (size_t)(n0 + row) * K + k0 + kk);
      Bs[kk + 0][row] = bv.x; Bs[kk + 1][row] = bv.y;
      Bs[kk + 2][row] = bv.z; Bs[kk + 3][row] = bv.w;
    }
    __syncthreads();
    #pragma unroll
    for (int kk = 0; kk < 32; ++kk) {
      float a[8], bq[8];
      *(float4*)(a)      = *(const float4*)(&As[kk][(ty << 3)]);
      *(float4*)(a + 4)  = *(const float4*)(&As[kk][(ty << 3) + 4]);
      *(float4*)(bq)     = *(const float4*)(&Bs[kk][(tx << 3)]);
      *(float4*)(bq + 4) = *(const float4*)(&Bs[kk][(tx << 3) + 4]);
      #pragma unroll
      for (int i = 0; i < 8; ++i)
        #pragma unroll
        for (int j = 0; j < 8; ++j)
          acc[i][j] = fmaf(a[i], bq[j], acc[i][j]);
    }
    __syncthreads();
  }

  #pragma unroll
  for (int i = 0; i < 8; ++i) {
    int row = m0 + (ty << 3) + i;
    #pragma unroll
    for (int j4 = 0; j4 < 2; ++j4) {
      int col = n0 + (tx << 3) + (j4 << 2);
      float4 r;
      float bbv[4];
      #pragma unroll
      for (int j = 0; j < 4; ++j)
        bbv[j] = (MODE == 0) ? bias_sel0(b0, b1, col + j) : b0[col + j];
      r.x = acc[i][j4 * 4 + 0] + bbv[0];
      r.y = acc[i][j4 * 4 + 1] + bbv[1];
      r.z = acc[i][j4 * 4 + 2] + bbv[2];
      r.w = acc[i][j4 * 4 + 3] + bbv[3];
      *(float4*)(C + (size_t)row * N + col) = r;
    }
  }
}

// ---------------------------------------------------------------------------
// fp32 in-place qk norm (tiers 2/3)
// ---------------------------------------------------------------------------
__global__ __launch_bounds__(256)
void qk_norm(float* __restrict__ qkv, const float* __restrict__ scale_mul)
{
  int wave = (blockIdx.x << 2) + (threadIdx.x >> 6);
  int lane = threadIdx.x & 63;
  int h  = wave & 15;
  int bl = wave >> 4;
  size_t base = (size_t)bl * 3072 + (h << 6) + lane;
  float q = qkv[base];
  float k = qkv[base + 1024];
  float sq = q * q, sk = k * k;
  #pragma unroll
  for (int off = 32; off; off >>= 1) {
    sq += __shfl_xor(sq, off);
    sk += __shfl_xor(sk, off);
  }
  float sm = __expf(fminf(scale_mul[h], LN100));
  q = q / fmaxf(sqrtf(sq), 1e-12f) * sm;
  k = k / fmaxf(sqrtf(sk), 1e-12f);
  qkv[base]        = q;
  qkv[base + 1024] = k;
}

// ---------------------------------------------------------------------------
// fp32 flash attention (tiers 2/3). OUTMODE 0: fp32 out; 1: split bf16 out.
// ---------------------------------------------------------------------------
#define SW(r, c4) ((((c4) ^ ((r) >> 2)) & 15) << 2)

template <int OUTMODE>
__global__ __launch_bounds__(256)
void attn_fwd(const float* __restrict__ qkv, const float* __restrict__ bias,
              float* __restrict__ aout,
              unsigned short* __restrict__ ah, unsigned short* __restrict__ al)
{
  __shared__ float Qs[64][64];
  __shared__ float Ks[64][64];
  __shared__ float Vs[64][64];
  __shared__ float Ps[64][64];

  const int tid = threadIdx.x;
  const int tx = tid & 15, ty = tid >> 4;
  const int qt = blockIdx.x & 15;
  const int h  = (blockIdx.x >> 4) & 15;
  const int b  = blockIdx.x >> 8;
  const int q0 = qt << 6;

  #pragma unroll
  for (int u = 0; u < 4; ++u) {
    int f = tid + (u << 8);
    int r = f >> 4, c4 = f & 15;
    float4 v = *(const float4*)(qkv + (size_t)(b * 1024 + q0 + r) * 3072 + (h << 6) + (c4 << 2));
    *(float4*)(&Qs[r][SW(r, c4)]) = v;
  }

  float o[4][4];
  float mr[4], lr[4];
  #pragma unroll
  for (int i = 0; i < 4; ++i) {
    mr[i] = -3.0e38f; lr[i] = 0.0f;
    #pragma unroll
    for (int j = 0; j < 4; ++j) o[i][j] = 0.0f;
  }

  for (int kv0 = 0; kv0 < 1024; kv0 += 64) {
    __syncthreads();
    #pragma unroll
    for (int u = 0; u < 4; ++u) {
      int f = tid + (u << 8);
      int r = f >> 4, c4 = f & 15;
      size_t gb = (size_t)(b * 1024 + kv0 + r) * 3072 + (h << 6) + (c4 << 2);
      *(float4*)(&Ks[r][SW(r, c4)]) = *(const float4*)(qkv + gb + 1024);
      *(float4*)(&Vs[r][SW(r, c4)]) = *(const float4*)(qkv + gb + 2048);
    }
    __syncthreads();

    float s[4][4];
    #pragma unroll
    for (int i = 0; i < 4; ++i)
      #pragma unroll
      for (int j = 0; j < 4; ++j) s[i][j] = 0.0f;

    #pragma unroll 4
    for (int d4 = 0; d4 < 16; ++d4) {
      float4 qv[4], kv[4];
      #pragma unroll
      for (int i = 0; i < 4; ++i)
        qv[i] = *(const float4*)(&Qs[(ty << 2) + i][SW((ty << 2) + i, d4)]);
      #pragma unroll
      for (int j = 0; j < 4; ++j)
        kv[j] = *(const float4*)(&Ks[(tx << 2) + j][SW((tx << 2) + j, d4)]);
      #pragma unroll
      for (int i = 0; i < 4; ++i)
        #pragma unroll
        for (int j = 0; j < 4; ++j)
          s[i][j] += qv[i].x * kv[j].x + qv[i].y * kv[j].y +
                     qv[i].z * kv[j].z + qv[i].w * kv[j].w;
    }

    float p[4][4];
    #pragma unroll
    for (int i = 0; i < 4; ++i) {
      float4 bv = *(const float4*)(bias + (size_t)((h << 10) + q0 + (ty << 2) + i) * 1024
                                        + kv0 + (tx << 2));
      s[i][0] += bv.x; s[i][1] += bv.y; s[i][2] += bv.z; s[i][3] += bv.w;
      float mx = fmaxf(fmaxf(s[i][0], s[i][1]), fmaxf(s[i][2], s[i][3]));
      #pragma unroll
      for (int off = 1; off < 16; off <<= 1) mx = fmaxf(mx, __shfl_xor(mx, off));
      float mn = fmaxf(mr[i], mx);
      float alp = __expf(mr[i] - mn);
      float rs = 0.0f;
      #pragma unroll
      for (int j = 0; j < 4; ++j) { p[i][j] = __expf(s[i][j] - mn); rs += p[i][j]; }
      #pragma unroll
      for (int off = 1; off < 16; off <<= 1) rs += __shfl_xor(rs, off);
      lr[i] = lr[i] * alp + rs;
      mr[i] = mn;
      #pragma unroll
      for (int j = 0; j < 4; ++j) o[i][j] *= alp;
    }

    #pragma unroll
    for (int jj = 0; jj < 4; ++jj)
      #pragma unroll
      for (int i = 0; i < 4; ++i)
        Ps[(tx << 2) + jj][SW((tx << 2) + jj, ty) + i] = p[i][jj];
    __syncthreads();

    #pragma unroll 8
    for (int j = 0; j < 64; ++j) {
      float4 pv = *(const float4*)(&Ps[j][SW(j, ty)]);
      float4 vv = *(const float4*)(&Vs[j][SW(j, tx)]);
      o[0][0] += pv.x * vv.x; o[0][1] += pv.x * vv.y; o[0][2] += pv.x * vv.z; o[0][3] += pv.x * vv.w;
      o[1][0] += pv.y * vv.x; o[1][1] += pv.y * vv.y; o[1][2] += pv.y * vv.z; o[1][3] += pv.y * vv.w;
      o[2][0] += pv.z * vv.x; o[2][1] += pv.z * vv.y; o[2][2] += pv.z * vv.z; o[2][3] += pv.z * vv.w;
      o[3][0] += pv.w * vv.x; o[3][1] += pv.w * vv.y; o[3][2] += pv.w * vv.z; o[3][3] += pv.w * vv.w;
    }
  }

  #pragma unroll
  for (int i = 0; i < 4; ++i) {
    float inv = 1.0f / lr[i];
    float v0 = o[i][0] * inv, v1 = o[i][1] * inv, v2 = o[i][2] * inv, v3 = o[i][3] * inv;
    if (OUTMODE == 0) {
      float4 r; r.x = v0; r.y = v1; r.z = v2; r.w = v3;
      *(float4*)(aout + (size_t)(b * 1024 + q0 + (ty << 2) + i) * 1024 + (h << 6) + (tx << 2)) = r;
    } else {
      ushort4 hh, ll;
      hh.x = f2bf(v0); ll.x = f2bf(v0 - bf2f(hh.x));
      hh.y = f2bf(v1); ll.y = f2bf(v1 - bf2f(hh.y));
      hh.z = f2bf(v2); ll.z = f2bf(v2 - bf2f(hh.z));
      hh.w = f2bf(v3); ll.w = f2bf(v3 - bf2f(hh.w));
      size_t idx = (size_t)(b * 1024 + q0 + (ty << 2) + i) * 256 + (h << 4) + tx;
      ((ushort4*)ah)[idx] = hh;
      ((ushort4*)al)[idx] = ll;
    }
  }
}

// ---------------------------------------------------------------------------
extern "C" void kernel_launch(void* const* d_in, const int* in_sizes, int n_in,
                              void* d_out, int out_size, void* d_ws, size_t ws_size,
                              hipStream_t stream) {
  const float* x         = (const float*)d_in[0];
  const float* attn_bias = (const float*)d_in[1];
  const float* w_qkv     = (const float*)d_in[2];
  const float* q_bias    = (const float*)d_in[3];
  const float* v_bias    = (const float*)d_in[4];
  const float* scale_mul = (const float*)d_in[5];
  const float* w_proj    = (const float*)d_in[6];
  const float* b_proj    = (const float*)d_in[7];
  float* out = (float*)d_out;

  const size_t MiB = 1024 * 1024;
  char* ws = (char*)d_ws;
  dim3 blk(256);

  if (ws_size >= 240 * MiB) {
    // ---- tier 1: full MFMA path (no fp32 qkv intermediate) ----
    unsigned short* xh  = (unsigned short*)(ws + 96  * MiB);  // -> att_h
    unsigned short* xl  = (unsigned short*)(ws + 112 * MiB);  // -> att_l
    unsigned short* qkh = (unsigned short*)(ws + 128 * MiB);
    unsigned short* qkl = (unsigned short*)(ws + 160 * MiB);
    unsigned short* vth = (unsigned short*)(ws + 192 * MiB);
    unsigned short* vtl = (unsigned short*)(ws + 208 * MiB);
    unsigned short* wqh = (unsigned short*)(ws + 224 * MiB);
    unsigned short* wql = (unsigned short*)(ws + 230 * MiB);
    unsigned short* wph = (unsigned short*)(ws + 236 * MiB);
    unsigned short* wpl = (unsigned short*)(ws + 238 * MiB);

    split_f32_bf16<<<dim3(8192), blk, 0, stream>>>(x,      xh,  xl,  2097152);
    split_f32_bf16<<<dim3(3072), blk, 0, stream>>>(w_qkv,  wqh, wql, 786432);
    split_f32_bf16<<<dim3(1024), blk, 0, stream>>>(w_proj, wph, wpl, 262144);

    // qkv GEMM: q/k -> fused norm+split qkh/qkl; V -> vth/vtl (perm split)
    gemm_nt_split<0><<<dim3(24, 64), blk, 0, stream>>>(xh, xl, wqh, wql,
        q_bias, v_bias, scale_mul, nullptr, qkh, qkl, vth, vtl, 8192, 3072, 1024);
    attn_mfma<<<dim3(1024), blk, 0, stream>>>(qkh, qkl, vth, vtl, attn_bias, xh, xl);
    gemm_nt_split<1><<<dim3(8, 64), blk, 0, stream>>>(xh, xl, wph, wpl,
        b_proj, nullptr, nullptr, out, nullptr, nullptr, nullptr, nullptr,
        8192, 1024, 1024);
  } else if (ws_size >= 144 * MiB) {
    // ---- tier 2: MFMA GEMMs + fp32 attention ----
    float*          qkv = (float*)ws;
    unsigned short* xh  = (unsigned short*)(ws + 96  * MiB);
    unsigned short* xl  = (unsigned short*)(ws + 112 * MiB);
    unsigned short* wqh = (unsigned short*)(ws + 128 * MiB);
    unsigned short* wql = (unsigned short*)(ws + 134 * MiB);
    unsigned short* wph = (unsigned short*)(ws + 140 * MiB);
    unsigned short* wpl = (unsigned short*)(ws + 142 * MiB);

    split_f32_bf16<<<dim3(8192), blk, 0, stream>>>(x,      xh,  xl,  2097152);
    split_f32_bf16<<<dim3(3072), blk, 0, stream>>>(w_qkv,  wqh, wql, 786432);
    split_f32_bf16<<<dim3(1024), blk, 0, stream>>>(w_proj, wph, wpl, 262144);

    gemm_nt_split<2><<<dim3(24, 64), blk, 0, stream>>>(xh, xl, wqh, wql,
        q_bias, v_bias, nullptr, qkv, nullptr, nullptr, nullptr, nullptr,
        8192, 3072, 1024);
    qk_norm<<<dim3(32768), blk, 0, stream>>>(qkv, scale_mul);
    attn_fwd<1><<<dim3(2048), blk, 0, stream>>>(qkv, attn_bias, nullptr, xh, xl);
    gemm_nt_split<1><<<dim3(8, 64), blk, 0, stream>>>(xh, xl, wph, wpl,
        b_proj, nullptr, nullptr, out, nullptr, nullptr, nullptr, nullptr,
        8192, 1024, 1024);
  } else {
    // ---- tier 3: pure fp32 ----
    float* qkv = (float*)ws;
    float* att = qkv + (size_t)8192 * 3072;
    gemm_nt<0><<<dim3(24, 64), blk, 0, stream>>>(x, w_qkv, q_bias, v_bias, qkv, 8192, 3072, 1024);
    qk_norm<<<dim3(32768), blk, 0, stream>>>(qkv, scale_mul);
    attn_fwd<0><<<dim3(2048), blk, 0, stream>>>(qkv, attn_bias, att, nullptr, nullptr);
    gemm_nt<1><<<dim3(8, 64), blk, 0, stream>>>(att, w_proj, b_proj, nullptr, out, 8192, 1024, 1024);
  }
}